// Round 7
// baseline (633.852 us; speedup 1.0000x reference)
//
#include <hip/hip_runtime.h>
#include <hip/hip_bf16.h>

// ---------------------------------------------------------------------------
// GAT 2-layer forward on MI355X (gfx950).
// R12: degree-sorted striped aggregate, zero per-dst-slice overhead.
//   - R9/R10/R11 lesson: bid%8->XCD striping fixes traffic (FETCH 199->44MB,
//     3x confirmed) but any per-dst work replicated NSx kills it.
//   - Counting-sort dsts by degree -> perm/inv; CSR rebuilt in perm order
//     (off2 over deg[perm[k]]+1) so sw stays a sequential stream in k.
//   - aggregate: 4 lanes/edge (16B half8 = full 64B slice row), 16 dsts per
//     wave from the SAME degree bin -> equal loop lengths, no divergence,
//     no padding. No LDS, no barriers, no reduce (each lane owns 8 cols,
//     wsum group-identical). Tail = normalize+bias+one 16B store per lane.
// R10: wkernel precomputes {src, exp(lrelu(as+ad))} once per edge per head.
// R9:  h sliced [HC/32][N][32]; gemm writes sliced, gemm2 reads sliced.
// fp16 intermediates, MFMA f16 GEMMs + fused att-logit epilogue, softmax
// shift-invariance (no max pass), end-normalization (no denom pass).
// ---------------------------------------------------------------------------

typedef _Float16 half8v __attribute__((ext_vector_type(8)));
typedef _Float16 half4v __attribute__((ext_vector_type(4)));
typedef float f32x4 __attribute__((ext_vector_type(4)));
typedef float f32x2 __attribute__((ext_vector_type(2)));

// --- MFMA GEMM + fused attention logits ------------------------------------

template <typename TA, int H>
__global__ __launch_bounds__(256) void gemm_att_kernel(
    const TA* __restrict__ A,
    const float* __restrict__ B,     // [H*128, K] row-major fp32 weights
    _Float16* __restrict__ C,        // SLICED [NCOL/32][M][32] fp16 out
    const float* __restrict__ att_s, // [H*128]
    const float* __restrict__ att_d, // [H*128]
    float* __restrict__ a_s,         // [M*H]
    float* __restrict__ a_d,         // [M*H]
    int M, int K, int GB)            // GB = GEMM blocks per head
{
    constexpr int BM = 128, BK = 32, LDA = 40;   // 40 f16 = 80 B = 5*16 B
    __shared__ _Float16 Ah[BM * LDA];
    __shared__ _Float16 Bh[BM * LDA];
    __shared__ float red[2][2][64][2];           // [wm][wn][row][s|d]

    const int tid = threadIdx.x;
    const int bid = blockIdx.x;

    // head-pair swizzle: (m,0) and (m,1) land 8 bids apart -> same XCD.
    int m0, by;
    if (H == 2 && (GB & 7) == 0) {
        const int cc = bid >> 4, jj = bid & 15;
        m0 = ((cc << 3) + (jj & 7)) * BM;
        by = jj >> 3;
    } else {
        m0 = (bid % GB) * BM;
        by = bid / GB;
    }
    const int n0 = by * 128;
    const int w  = tid >> 6;
    const int l  = tid & 63;
    const int wm = (w >> 1) * 64;
    const int wn = (w & 1) * 64;
    const int lr = l & 15;
    const int lq = l >> 4;

    f32x4 acc[4][4] = {};

    for (int k0 = 0; k0 < K; k0 += BK) {
        if constexpr (__is_same(TA, float)) {
#pragma unroll
            for (int it = 0; it < 4; ++it) {
                const int row = (tid >> 3) + it * 32;
                const int gm  = min(m0 + row, M - 1);
                const int c4  = (tid & 7) * 4;
                float4 v = *reinterpret_cast<const float4*>(A + (long)gm * K + k0 + c4);
                half4v o = { (_Float16)v.x, (_Float16)v.y, (_Float16)v.z, (_Float16)v.w };
                *reinterpret_cast<half4v*>(&Ah[row * LDA + c4]) = o;
            }
        } else {
            // sliced A: [K/32][M][32]; BK==32 -> one chunk per k-step
#pragma unroll
            for (int it = 0; it < 2; ++it) {
                const int row = (tid >> 2) + it * 64;
                const int gm  = min(m0 + row, M - 1);
                const int c8  = (tid & 3) * 8;
                const _Float16* src = (const _Float16*)A +
                    ((size_t)(k0 >> 5) * M + gm) * 32 + c8;
                float4 v = *reinterpret_cast<const float4*>(src);
                *reinterpret_cast<float4*>(&Ah[row * LDA + c8]) = v;
            }
        }
#pragma unroll
        for (int it = 0; it < 4; ++it) {
            const int row = (tid >> 3) + it * 32;
            const int c4  = (tid & 7) * 4;
            float4 v = *reinterpret_cast<const float4*>(B + (long)(n0 + row) * K + k0 + c4);
            half4v o = { (_Float16)v.x, (_Float16)v.y, (_Float16)v.z, (_Float16)v.w };
            *reinterpret_cast<half4v*>(&Bh[row * LDA + c4]) = o;
        }
        __syncthreads();

        half8v af[4], bf[4];
#pragma unroll
        for (int i = 0; i < 4; ++i)
            af[i] = *reinterpret_cast<const half8v*>(&Ah[(wm + i * 16 + lr) * LDA + lq * 8]);
#pragma unroll
        for (int j = 0; j < 4; ++j)
            bf[j] = *reinterpret_cast<const half8v*>(&Bh[(wn + j * 16 + lr) * LDA + lq * 8]);
#pragma unroll
        for (int i = 0; i < 4; ++i)
#pragma unroll
            for (int j = 0; j < 4; ++j)
                acc[i][j] = __builtin_amdgcn_mfma_f32_16x16x32_f16(af[i], bf[j], acc[i][j], 0, 0, 0);
        __syncthreads();
    }

    // ---- store C (sliced [NCOL/32][M][32]) ----
#pragma unroll
    for (int i = 0; i < 4; ++i) {
        const int gm_base = m0 + wm + i * 16 + lq * 4;
#pragma unroll
        for (int r = 0; r < 4; ++r) {
            const int gm = gm_base + r;
            if (gm < M) {
#pragma unroll
                for (int j = 0; j < 4; ++j) {
                    const int col = n0 + wn + j * 16 + lr;
                    C[((size_t)(col >> 5) * M + gm) * 32 + (col & 31)] =
                        (_Float16)acc[i][j][r];
                }
            }
        }
    }

    // ---- fused attention logits ----
    float asv[4], adv[4];
#pragma unroll
    for (int j = 0; j < 4; ++j) {
        asv[j] = att_s[n0 + wn + j * 16 + lr];
        adv[j] = att_d[n0 + wn + j * 16 + lr];
    }
    float ps[4][4] = {}, pd[4][4] = {};
#pragma unroll
    for (int i = 0; i < 4; ++i)
#pragma unroll
        for (int j = 0; j < 4; ++j)
#pragma unroll
            for (int r = 0; r < 4; ++r) {
                ps[i][r] += acc[i][j][r] * asv[j];
                pd[i][r] += acc[i][j][r] * adv[j];
            }
#pragma unroll
    for (int o = 1; o < 16; o <<= 1)
#pragma unroll
        for (int i = 0; i < 4; ++i)
#pragma unroll
            for (int r = 0; r < 4; ++r) {
                ps[i][r] += __shfl_xor(ps[i][r], o, 64);
                pd[i][r] += __shfl_xor(pd[i][r], o, 64);
            }
    if (lr == 0) {
#pragma unroll
        for (int i = 0; i < 4; ++i)
#pragma unroll
            for (int r = 0; r < 4; ++r) {
                const int row = i * 16 + lq * 4 + r;
                red[wm >> 6][wn >> 6][row][0] = ps[i][r];
                red[wm >> 6][wn >> 6][row][1] = pd[i][r];
            }
    }
    __syncthreads();
    if (wn == 0) {                       // waves 0 and 2 cover wm = 0, 64
        const int row = l;
        const int gm = m0 + wm + row;
        if (gm < M) {
            const int wi = wm >> 6;
            a_s[(long)gm * H + by] = red[wi][0][row][0] + red[wi][1][row][0];
            a_d[(long)gm * H + by] = red[wi][0][row][1] + red[wi][1][row][1];
        }
    }
}

// --- CSR build --------------------------------------------------------------

// count + rank: rank[e] = position of edge e within its dst's neighborhood
__global__ void count_kernel(const int* __restrict__ dst, int* __restrict__ deg,
                             int* __restrict__ rank, int E)
{
    const int tid = blockIdx.x * blockDim.x + threadIdx.x;
    const int e4 = tid * 4;
    if (e4 + 3 < E) {
        const int4 d = *reinterpret_cast<const int4*>(dst + e4);
        int4 r;
        r.x = atomicAdd(&deg[d.x], 1);
        r.y = atomicAdd(&deg[d.y], 1);
        r.z = atomicAdd(&deg[d.z], 1);
        r.w = atomicAdd(&deg[d.w], 1);
        *reinterpret_cast<int4*>(rank + e4) = r;
    } else if (e4 < E) {
        for (int k = e4; k < E; ++k) rank[k] = atomicAdd(&deg[dst[k]], 1);
    }
}

// --- degree counting sort ---------------------------------------------------

__global__ void hist_kernel(const int* __restrict__ deg, int* __restrict__ hist, int n)
{
    const int i = blockIdx.x * 256 + threadIdx.x;
    if (i < n) atomicAdd(&hist[min(deg[i], 255)], 1);
}

// single block: exclusive scan of 256 bins -> binstart; copy to bincur
__global__ __launch_bounds__(256) void scan256_kernel(
    const int* __restrict__ hist, int* __restrict__ bincur)
{
    __shared__ int s[256];
    const int t = threadIdx.x;
    s[t] = hist[t];
    __syncthreads();
#pragma unroll
    for (int o = 1; o < 256; o <<= 1) {
        int v = 0;
        if (t >= o) v = s[t - o];
        __syncthreads();
        s[t] += v;
        __syncthreads();
    }
    bincur[t] = (t == 0) ? 0 : s[t - 1];
}

__global__ void scatter_perm_kernel(const int* __restrict__ deg,
                                    int* __restrict__ bincur,
                                    int* __restrict__ perm,
                                    int* __restrict__ inv, int n)
{
    const int i = blockIdx.x * 256 + threadIdx.x;
    if (i < n) {
        const int b = min(deg[i], 255);
        const int pos = atomicAdd(&bincur[b], 1);
        perm[pos] = i;
        inv[i] = pos;
    }
}

// per-block exclusive scan of (deg[perm[k]]+1), 1024 elems/block
__global__ __launch_bounds__(256) void block_scan_perm_kernel(
    const int* __restrict__ deg, const int* __restrict__ perm,
    int* __restrict__ pre, int* __restrict__ blk, int n)
{
    __shared__ int s[256];
    const int t = threadIdx.x;
    const int base = blockIdx.x * 1024 + t * 4;
    int4 d = make_int4(-1, -1, -1, -1);   // +1 -> 0 contribution OOB
    if (base + 3 < n) {
        const int4 p = *reinterpret_cast<const int4*>(perm + base);
        d.x = deg[p.x]; d.y = deg[p.y]; d.z = deg[p.z]; d.w = deg[p.w];
    } else {
        if (base + 0 < n) d.x = deg[perm[base + 0]];
        if (base + 1 < n) d.y = deg[perm[base + 1]];
        if (base + 2 < n) d.z = deg[perm[base + 2]];
        if (base + 3 < n) d.w = deg[perm[base + 3]];
    }
    const int v0 = d.x + 1, v1 = d.y + 1, v2 = d.z + 1, v3 = d.w + 1;
    s[t] = v0 + v1 + v2 + v3;
    __syncthreads();
#pragma unroll
    for (int o = 1; o < 256; o <<= 1) {
        int val = 0;
        if (t >= o) val = s[t - o];
        __syncthreads();
        s[t] += val;
        __syncthreads();
    }
    int run = (t == 0) ? 0 : s[t - 1];
    int4 o4;
    o4.x = run; run += v0;
    o4.y = run; run += v1;
    o4.z = run; run += v2;
    o4.w = run; run += v3;
    if (base + 3 < n) *reinterpret_cast<int4*>(pre + base) = o4;
    else {
        if (base + 0 < n) pre[base + 0] = o4.x;
        if (base + 1 < n) pre[base + 1] = o4.y;
        if (base + 2 < n) pre[base + 2] = o4.z;
        if (base + 3 < n) pre[base + 3] = o4.w;
    }
    if (t == 255) blk[blockIdx.x] = s[255];
}

// finalize: add prefix of block totals; emit off2 (permuted CSR offsets)
__global__ __launch_bounds__(256) void finalize_scan_kernel(
    const int* __restrict__ pre, const int* __restrict__ blk,
    int* __restrict__ off, int n, int nvb)
{
    __shared__ int s_add;
    const int vb = blockIdx.x;
    const int t  = threadIdx.x;
    if (t < 64) {
        int v = (t < vb) ? blk[t] : 0;    // nvb <= 64
#pragma unroll
        for (int o = 32; o > 0; o >>= 1) v += __shfl_xor(v, o, 64);
        if (t == 0) s_add = v;
    }
    __syncthreads();
    const int add = s_add;
    const int base = vb * 1024 + t * 4;
    if (base + 3 < n) {
        int4 p = *reinterpret_cast<const int4*>(pre + base);
        p.x += add; p.y += add; p.z += add; p.w += add;
        *reinterpret_cast<int4*>(off + base) = p;
    } else {
#pragma unroll
        for (int k = 0; k < 4; ++k)
            if (base + k < n) off[base + k] = pre[base + k] + add;
    }
    if (vb == nvb - 1 && t == 0) off[n] = add + blk[vb];
}

// --- weight precompute (= scatter into permuted CSR order) ------------------
// idx < N: self-loop of dst idx at row start. idx in [N,N+E): edge at
// off2[inv[dst]] + 1 + rank.

template <int H>
__global__ __launch_bounds__(256) void wkernel(
    const int* __restrict__ esrc, const int* __restrict__ edst,
    const int* __restrict__ rank, const int* __restrict__ off2,
    const int* __restrict__ inv,
    const float* __restrict__ a_s, const float* __restrict__ a_d,
    f32x2* __restrict__ sw,          // [H][E+N] head-major
    int N, int E)
{
    const int idx = blockIdx.x * 256 + threadIdx.x;
    int s, dd, pos;
    if (idx < N) {
        s = idx; dd = idx; pos = off2[inv[idx]];
    } else if (idx < N + E) {
        const int e = idx - N;
        s = esrc[e]; dd = edst[e];
        pos = off2[inv[dd]] + 1 + rank[e];
    } else {
        return;
    }
#pragma unroll
    for (int h = 0; h < H; ++h) {
        float lg = a_s[s * H + h] + a_d[dd * H + h];
        lg = lg > 0.f ? lg : 0.2f * lg;
        f32x2 v = { __int_as_float(s), __expf(lg) };
        sw[(size_t)h * (N + E) + pos] = v;
    }
}

// --- XCD-striped pull aggregation (degree-sorted, zero-overhead) -----------
// h SLICED [HC/32][N][32]; slice = (bid%8)%NS -> XCD-resident stripe.
// 4-lane group owns dst perm[kb+g] (16 dsts/wave, same degree bin -> equal
// trip counts). Per edge: 8B sw broadcast + 16B half8 gather (group = full
// 64B row) + 8 FMA. No LDS/barrier/reduce; direct normalize + 16B store.

template <int H, int C, bool RELU, typename TOUT>
__global__ __launch_bounds__(256) void aggregate_kernel(
    const int* __restrict__ off2,    // [N+1] permuted CSR offsets
    const int* __restrict__ perm,    // [N] k -> original dst id
    const f32x2* __restrict__ sw,    // [H][E+N] head-major, permuted order
    const _Float16* __restrict__ h,  // sliced [HC/32][N][32] fp16
    const float* __restrict__ bias,  // [HC]
    TOUT* __restrict__ out,          // f16: sliced [HC/32][N][32]; f32: [N,HC]
    int N, int ENtot, int G8)        // G8 = gridDim.x / 8
{
    constexpr int HC  = H * C;
    constexpr int NS  = HC / 32;     // slices: 8 (L1), 4 (L2)
    constexpr int REP = 8 / NS;      // XCD groups per slice
    const int w  = threadIdx.x >> 6;
    const int l  = threadIdx.x & 63;
    const int g  = l >> 2;           // group 0..15 (4 lanes each)
    const int cl = (l & 3) * 8;      // col base within slice (8 cols)
    const int b8 = blockIdx.x & 7;
    const int slice = b8 % NS;
    const int hh = (slice * 32) / C; // head of this slice

    const f32x2*    __restrict__ swh = sw + (size_t)hh * ENtot;
    const _Float16* __restrict__ hs  = h + (size_t)slice * N * 32;

    const int wid  = ((blockIdx.x >> 3) * REP + b8 / NS) * 4 + w;
    const int nwav = G8 * REP * 4;   // waves per slice

    for (int kb = wid * 16; kb < N; kb += nwav * 16) {
        const int k = kb + g;
        const bool act = k < N;
        int beg = 0, end = 0, d = 0;
        if (act) { d = perm[k]; beg = off2[k]; end = off2[k + 1]; }

        float a0 = 0.f, a1 = 0.f, a2 = 0.f, a3 = 0.f;
        float a4 = 0.f, a5 = 0.f, a6 = 0.f, a7 = 0.f, ws = 0.f;
#pragma unroll 2
        for (int e = beg; e < end; ++e) {
            const f32x2 sv = swh[e];
            const int    s  = __float_as_int(sv.x);
            const float  wt = sv.y;
            const half8v hv = *reinterpret_cast<const half8v*>(
                hs + (size_t)s * 32 + cl);
            a0 += wt * (float)hv[0];
            a1 += wt * (float)hv[1];
            a2 += wt * (float)hv[2];
            a3 += wt * (float)hv[3];
            a4 += wt * (float)hv[4];
            a5 += wt * (float)hv[5];
            a6 += wt * (float)hv[6];
            a7 += wt * (float)hv[7];
            ws += wt;
        }

        if (act) {
            const float inv_ = 1.f / ws;
            const int cb = slice * 32 + cl;
            float r[8];
            r[0] = a0 * inv_ + bias[cb + 0];
            r[1] = a1 * inv_ + bias[cb + 1];
            r[2] = a2 * inv_ + bias[cb + 2];
            r[3] = a3 * inv_ + bias[cb + 3];
            r[4] = a4 * inv_ + bias[cb + 4];
            r[5] = a5 * inv_ + bias[cb + 5];
            r[6] = a6 * inv_ + bias[cb + 6];
            r[7] = a7 * inv_ + bias[cb + 7];
            if (RELU) {
#pragma unroll
                for (int q = 0; q < 8; ++q) r[q] = r[q] > 0.f ? r[q] : 0.f;
            }
            if constexpr (__is_same(TOUT, _Float16)) {
                half8v ov;
#pragma unroll
                for (int q = 0; q < 8; ++q) ov[q] = (_Float16)r[q];
                *reinterpret_cast<half8v*>(
                    out + ((size_t)slice * N + d) * 32 + cl) = ov;
            } else {
                f32x4 o0 = { r[0], r[1], r[2], r[3] };
                f32x4 o1 = { r[4], r[5], r[6], r[7] };
                float* po = out + (size_t)d * HC + slice * 32 + cl;
                *reinterpret_cast<f32x4*>(po)     = o0;
                *reinterpret_cast<f32x4*>(po + 4) = o1;
            }
        }
    }
}

// ---------------------------------------------------------------------------

extern "C" void kernel_launch(void* const* d_in, const int* in_sizes, int n_in,
                              void* d_out, int out_size, void* d_ws, size_t ws_size,
                              hipStream_t stream)
{
    const float* x    = (const float*)d_in[0];
    const int*   eidx = (const int*)d_in[1];
    const float* W1   = (const float*)d_in[2];
    const float* as1  = (const float*)d_in[3];
    const float* ad1  = (const float*)d_in[4];
    const float* b1   = (const float*)d_in[5];
    const float* W2   = (const float*)d_in[6];
    const float* as2  = (const float*)d_in[7];
    const float* ad2  = (const float*)d_in[8];
    const float* b2   = (const float*)d_in[9];
    float* out = (float*)d_out;

    const int IN_FEATS = 256;
    const int N = in_sizes[0] / IN_FEATS;    // 50000
    const int E = in_sizes[1] / 2;           // 800000
    const int EN = E + N;

    const int* esrc = eidx;
    const int* edst = eidx + E;

    size_t off = 0;
    auto alloc = [&](size_t bytes) -> void* {
        void* p = (char*)d_ws + off;
        off += (bytes + 255) & ~(size_t)255;
        return p;
    };
    _Float16* h1h   = (_Float16*)alloc((size_t)N * 256 * 2);   // sliced [8][N][32]
    _Float16* o1h   = (_Float16*)alloc((size_t)N * 256 * 2);   // sliced [8][N][32]
    _Float16* h2h   = (_Float16*)alloc((size_t)N * 128 * 2);   // sliced [4][N][32]
    float* a1s      = (float*)alloc((size_t)N * 2 * 4);
    float* a1d      = (float*)alloc((size_t)N * 2 * 4);
    float* a2s      = (float*)alloc((size_t)N * 4);
    float* a2d      = (float*)alloc((size_t)N * 4);
    int*   deg      = (int*)alloc((size_t)N * 4);
    int*   pre      = (int*)alloc((size_t)N * 4);
    int*   rank     = (int*)alloc((size_t)E * 4);
    int*   off2     = (int*)alloc((size_t)(N + 1) * 4);
    int*   perm     = (int*)alloc((size_t)N * 4);
    int*   invp     = (int*)alloc((size_t)N * 4);
    int*   hist     = (int*)alloc(256 * 4);
    int*   bincur   = (int*)alloc(256 * 4);
    f32x2* sw1      = (f32x2*)alloc((size_t)2 * EN * 8);       // [2][E+N]
    int*   blk      = (int*)alloc(64 * 4);
    // sw2 aliases h1h (h1h dead after agg1; wkernel<1>/agg2 run later)
    f32x2* sw2      = (f32x2*)h1h;                             // [1][E+N]

    const int nvb = (N + 1023) / 1024;    // 49 <= 64

    // --- CSR offsets + ranks + degree counting sort ---
    (void)hipMemsetAsync(deg, 0, (size_t)N * 4, stream);
    (void)hipMemsetAsync(hist, 0, 256 * 4, stream);
    count_kernel<<<((E + 3) / 4 + 255) / 256, 256, 0, stream>>>(edst, deg, rank, E);
    hist_kernel<<<(N + 255) / 256, 256, 0, stream>>>(deg, hist, N);
    scan256_kernel<<<1, 256, 0, stream>>>(hist, bincur);
    scatter_perm_kernel<<<(N + 255) / 256, 256, 0, stream>>>(deg, bincur, perm, invp, N);
    block_scan_perm_kernel<<<nvb, 256, 0, stream>>>(deg, perm, pre, blk, N);
    finalize_scan_kernel<<<nvb, 256, 0, stream>>>(pre, blk, off2, N, nvb);

    // --- layer 1 ---
    {
        const int GB = (N + 127) / 128;      // 392 (multiple of 8)
        gemm_att_kernel<float, 2><<<GB * 2, 256, 0, stream>>>(
            x, W1, h1h, as1, ad1, a1s, a1d, N, 256, GB);
    }
    wkernel<2><<<(EN + 255) / 256, 256, 0, stream>>>(
        esrc, edst, rank, off2, invp, a1s, a1d, sw1, N, E);
    {
        const int G8 = 256;                  // 2048 blocks co-resident
        aggregate_kernel<2, 128, true, _Float16><<<G8 * 8, 256, 0, stream>>>(
            off2, perm, sw1, h1h, b1, o1h, N, EN, G8);
    }

    // --- layer 2 ---
    {
        const int GB = (N + 127) / 128;
        gemm_att_kernel<_Float16, 1><<<GB, 256, 0, stream>>>(
            o1h, W2, h2h, as2, ad2, a2s, a2d, N, 256, GB);
    }
    wkernel<1><<<(EN + 255) / 256, 256, 0, stream>>>(
        esrc, edst, rank, off2, invp, a2s, a2d, sw2, N, E);
    {
        const int G8 = 256;
        aggregate_kernel<1, 128, false, float><<<G8 * 8, 256, 0, stream>>>(
            off2, perm, sw2, h2h, b2, out, N, EN, G8);
    }
}

// Round 8
// 365.253 us; speedup vs baseline: 1.7354x; 1.7354x over previous
//
#include <hip/hip_runtime.h>
#include <hip/hip_bf16.h>

// ---------------------------------------------------------------------------
// GAT 2-layer forward on MI355X (gfx950).
// R13: fix counting-sort atomics contention (scatter_perm was 133us: 50K
//      device atomics on ~40 hot bins). hist + scatter now LDS-aggregate
//      per block first (Guideline 12), then <=256 spread global atomics per
//      block. Within-bin order becomes nondeterministic -> harmless (perm
//      only groups equal-degree dsts; all consumers use the same perm).
// R12: degree-sorted striped aggregate, zero per-dst-slice overhead.
//      4 lanes/edge, 16 same-bin dsts/wave, no LDS/barrier/reduce.
// R10: wkernel precomputes {src, exp(lrelu(as+ad))} once per edge per head.
// R9:  h sliced [HC/32][N][32], bid%8->XCD striping (traffic 3x confirmed).
// fp16 intermediates, MFMA f16 GEMMs + fused att-logit epilogue, softmax
// shift-invariance (no max pass), end-normalization (no denom pass).
// ---------------------------------------------------------------------------

typedef _Float16 half8v __attribute__((ext_vector_type(8)));
typedef _Float16 half4v __attribute__((ext_vector_type(4)));
typedef float f32x4 __attribute__((ext_vector_type(4)));
typedef float f32x2 __attribute__((ext_vector_type(2)));

// --- MFMA GEMM + fused attention logits ------------------------------------

template <typename TA, int H>
__global__ __launch_bounds__(256) void gemm_att_kernel(
    const TA* __restrict__ A,
    const float* __restrict__ B,     // [H*128, K] row-major fp32 weights
    _Float16* __restrict__ C,        // SLICED [NCOL/32][M][32] fp16 out
    const float* __restrict__ att_s, // [H*128]
    const float* __restrict__ att_d, // [H*128]
    float* __restrict__ a_s,         // [M*H]
    float* __restrict__ a_d,         // [M*H]
    int M, int K, int GB)            // GB = GEMM blocks per head
{
    constexpr int BM = 128, BK = 32, LDA = 40;   // 40 f16 = 80 B = 5*16 B
    __shared__ _Float16 Ah[BM * LDA];
    __shared__ _Float16 Bh[BM * LDA];
    __shared__ float red[2][2][64][2];           // [wm][wn][row][s|d]

    const int tid = threadIdx.x;
    const int bid = blockIdx.x;

    // head-pair swizzle: (m,0) and (m,1) land 8 bids apart -> same XCD.
    int m0, by;
    if (H == 2 && (GB & 7) == 0) {
        const int cc = bid >> 4, jj = bid & 15;
        m0 = ((cc << 3) + (jj & 7)) * BM;
        by = jj >> 3;
    } else {
        m0 = (bid % GB) * BM;
        by = bid / GB;
    }
    const int n0 = by * 128;
    const int w  = tid >> 6;
    const int l  = tid & 63;
    const int wm = (w >> 1) * 64;
    const int wn = (w & 1) * 64;
    const int lr = l & 15;
    const int lq = l >> 4;

    f32x4 acc[4][4] = {};

    for (int k0 = 0; k0 < K; k0 += BK) {
        if constexpr (__is_same(TA, float)) {
#pragma unroll
            for (int it = 0; it < 4; ++it) {
                const int row = (tid >> 3) + it * 32;
                const int gm  = min(m0 + row, M - 1);
                const int c4  = (tid & 7) * 4;
                float4 v = *reinterpret_cast<const float4*>(A + (long)gm * K + k0 + c4);
                half4v o = { (_Float16)v.x, (_Float16)v.y, (_Float16)v.z, (_Float16)v.w };
                *reinterpret_cast<half4v*>(&Ah[row * LDA + c4]) = o;
            }
        } else {
            // sliced A: [K/32][M][32]; BK==32 -> one chunk per k-step
#pragma unroll
            for (int it = 0; it < 2; ++it) {
                const int row = (tid >> 2) + it * 64;
                const int gm  = min(m0 + row, M - 1);
                const int c8  = (tid & 3) * 8;
                const _Float16* src = (const _Float16*)A +
                    ((size_t)(k0 >> 5) * M + gm) * 32 + c8;
                float4 v = *reinterpret_cast<const float4*>(src);
                *reinterpret_cast<float4*>(&Ah[row * LDA + c8]) = v;
            }
        }
#pragma unroll
        for (int it = 0; it < 4; ++it) {
            const int row = (tid >> 3) + it * 32;
            const int c4  = (tid & 7) * 4;
            float4 v = *reinterpret_cast<const float4*>(B + (long)(n0 + row) * K + k0 + c4);
            half4v o = { (_Float16)v.x, (_Float16)v.y, (_Float16)v.z, (_Float16)v.w };
            *reinterpret_cast<half4v*>(&Bh[row * LDA + c4]) = o;
        }
        __syncthreads();

        half8v af[4], bf[4];
#pragma unroll
        for (int i = 0; i < 4; ++i)
            af[i] = *reinterpret_cast<const half8v*>(&Ah[(wm + i * 16 + lr) * LDA + lq * 8]);
#pragma unroll
        for (int j = 0; j < 4; ++j)
            bf[j] = *reinterpret_cast<const half8v*>(&Bh[(wn + j * 16 + lr) * LDA + lq * 8]);
#pragma unroll
        for (int i = 0; i < 4; ++i)
#pragma unroll
            for (int j = 0; j < 4; ++j)
                acc[i][j] = __builtin_amdgcn_mfma_f32_16x16x32_f16(af[i], bf[j], acc[i][j], 0, 0, 0);
        __syncthreads();
    }

    // ---- store C (sliced [NCOL/32][M][32]) ----
#pragma unroll
    for (int i = 0; i < 4; ++i) {
        const int gm_base = m0 + wm + i * 16 + lq * 4;
#pragma unroll
        for (int r = 0; r < 4; ++r) {
            const int gm = gm_base + r;
            if (gm < M) {
#pragma unroll
                for (int j = 0; j < 4; ++j) {
                    const int col = n0 + wn + j * 16 + lr;
                    C[((size_t)(col >> 5) * M + gm) * 32 + (col & 31)] =
                        (_Float16)acc[i][j][r];
                }
            }
        }
    }

    // ---- fused attention logits ----
    float asv[4], adv[4];
#pragma unroll
    for (int j = 0; j < 4; ++j) {
        asv[j] = att_s[n0 + wn + j * 16 + lr];
        adv[j] = att_d[n0 + wn + j * 16 + lr];
    }
    float ps[4][4] = {}, pd[4][4] = {};
#pragma unroll
    for (int i = 0; i < 4; ++i)
#pragma unroll
        for (int j = 0; j < 4; ++j)
#pragma unroll
            for (int r = 0; r < 4; ++r) {
                ps[i][r] += acc[i][j][r] * asv[j];
                pd[i][r] += acc[i][j][r] * adv[j];
            }
#pragma unroll
    for (int o = 1; o < 16; o <<= 1)
#pragma unroll
        for (int i = 0; i < 4; ++i)
#pragma unroll
            for (int r = 0; r < 4; ++r) {
                ps[i][r] += __shfl_xor(ps[i][r], o, 64);
                pd[i][r] += __shfl_xor(pd[i][r], o, 64);
            }
    if (lr == 0) {
#pragma unroll
        for (int i = 0; i < 4; ++i)
#pragma unroll
            for (int r = 0; r < 4; ++r) {
                const int row = i * 16 + lq * 4 + r;
                red[wm >> 6][wn >> 6][row][0] = ps[i][r];
                red[wm >> 6][wn >> 6][row][1] = pd[i][r];
            }
    }
    __syncthreads();
    if (wn == 0) {                       // waves 0 and 2 cover wm = 0, 64
        const int row = l;
        const int gm = m0 + wm + row;
        if (gm < M) {
            const int wi = wm >> 6;
            a_s[(long)gm * H + by] = red[wi][0][row][0] + red[wi][1][row][0];
            a_d[(long)gm * H + by] = red[wi][0][row][1] + red[wi][1][row][1];
        }
    }
}

// --- CSR build --------------------------------------------------------------

// count + rank: rank[e] = position of edge e within its dst's neighborhood
__global__ void count_kernel(const int* __restrict__ dst, int* __restrict__ deg,
                             int* __restrict__ rank, int E)
{
    const int tid = blockIdx.x * blockDim.x + threadIdx.x;
    const int e4 = tid * 4;
    if (e4 + 3 < E) {
        const int4 d = *reinterpret_cast<const int4*>(dst + e4);
        int4 r;
        r.x = atomicAdd(&deg[d.x], 1);
        r.y = atomicAdd(&deg[d.y], 1);
        r.z = atomicAdd(&deg[d.z], 1);
        r.w = atomicAdd(&deg[d.w], 1);
        *reinterpret_cast<int4*>(rank + e4) = r;
    } else if (e4 < E) {
        for (int k = e4; k < E; ++k) rank[k] = atomicAdd(&deg[dst[k]], 1);
    }
}

// --- degree counting sort (LDS-aggregated, Guideline 12) --------------------

// per-block 256-bin LDS histogram of 1024 nodes -> <=256 global atomics/block
__global__ __launch_bounds__(256) void hist_kernel(
    const int* __restrict__ deg, int* __restrict__ hist, int n)
{
    __shared__ int lh[256];
    const int t = threadIdx.x;
    lh[t] = 0;
    __syncthreads();
    const int base = blockIdx.x * 1024;
    const int lim  = min(base + 1024, n);
    for (int i = base + t; i < lim; i += 256)
        atomicAdd(&lh[min(deg[i], 255)], 1);
    __syncthreads();
    const int c = lh[t];
    if (c) atomicAdd(&hist[t], c);
}

// single block: exclusive scan of 256 bins -> bincur
__global__ __launch_bounds__(256) void scan256_kernel(
    const int* __restrict__ hist, int* __restrict__ bincur)
{
    __shared__ int s[256];
    const int t = threadIdx.x;
    s[t] = hist[t];
    __syncthreads();
#pragma unroll
    for (int o = 1; o < 256; o <<= 1) {
        int v = 0;
        if (t >= o) v = s[t - o];
        __syncthreads();
        s[t] += v;
        __syncthreads();
    }
    bincur[t] = (t == 0) ? 0 : s[t - 1];
}

// two-pass LDS scatter: block reserves a range per bin with ONE global
// atomic, then assigns within-block ranks via LDS atomics.
__global__ __launch_bounds__(256) void scatter_perm_kernel(
    const int* __restrict__ deg, int* __restrict__ bincur,
    int* __restrict__ perm, int* __restrict__ inv, int n)
{
    __shared__ int lh[256];
    __shared__ int lbase[256];
    const int t = threadIdx.x;
    lh[t] = 0;
    __syncthreads();
    const int base = blockIdx.x * 1024;
    const int lim  = min(base + 1024, n);
    int mybin[4];
    int cnt = 0;
    for (int i = base + t; i < lim; i += 256) {
        const int b = min(deg[i], 255);
        mybin[cnt++] = b;
        atomicAdd(&lh[b], 1);
    }
    __syncthreads();
    const int c = lh[t];
    if (c) lbase[t] = atomicAdd(&bincur[t], c);
    __syncthreads();
    lh[t] = 0;
    __syncthreads();
    cnt = 0;
    for (int i = base + t; i < lim; i += 256) {
        const int b = mybin[cnt++];
        const int pos = lbase[b] + atomicAdd(&lh[b], 1);
        perm[pos] = i;
        inv[i] = pos;
    }
}

// per-block exclusive scan of (deg[perm[k]]+1), 1024 elems/block
__global__ __launch_bounds__(256) void block_scan_perm_kernel(
    const int* __restrict__ deg, const int* __restrict__ perm,
    int* __restrict__ pre, int* __restrict__ blk, int n)
{
    __shared__ int s[256];
    const int t = threadIdx.x;
    const int base = blockIdx.x * 1024 + t * 4;
    int4 d = make_int4(-1, -1, -1, -1);   // +1 -> 0 contribution OOB
    if (base + 3 < n) {
        const int4 p = *reinterpret_cast<const int4*>(perm + base);
        d.x = deg[p.x]; d.y = deg[p.y]; d.z = deg[p.z]; d.w = deg[p.w];
    } else {
        if (base + 0 < n) d.x = deg[perm[base + 0]];
        if (base + 1 < n) d.y = deg[perm[base + 1]];
        if (base + 2 < n) d.z = deg[perm[base + 2]];
        if (base + 3 < n) d.w = deg[perm[base + 3]];
    }
    const int v0 = d.x + 1, v1 = d.y + 1, v2 = d.z + 1, v3 = d.w + 1;
    s[t] = v0 + v1 + v2 + v3;
    __syncthreads();
#pragma unroll
    for (int o = 1; o < 256; o <<= 1) {
        int val = 0;
        if (t >= o) val = s[t - o];
        __syncthreads();
        s[t] += val;
        __syncthreads();
    }
    int run = (t == 0) ? 0 : s[t - 1];
    int4 o4;
    o4.x = run; run += v0;
    o4.y = run; run += v1;
    o4.z = run; run += v2;
    o4.w = run; run += v3;
    if (base + 3 < n) *reinterpret_cast<int4*>(pre + base) = o4;
    else {
        if (base + 0 < n) pre[base + 0] = o4.x;
        if (base + 1 < n) pre[base + 1] = o4.y;
        if (base + 2 < n) pre[base + 2] = o4.z;
        if (base + 3 < n) pre[base + 3] = o4.w;
    }
    if (t == 255) blk[blockIdx.x] = s[255];
}

// finalize: add prefix of block totals; emit off2 (permuted CSR offsets)
__global__ __launch_bounds__(256) void finalize_scan_kernel(
    const int* __restrict__ pre, const int* __restrict__ blk,
    int* __restrict__ off, int n, int nvb)
{
    __shared__ int s_add;
    const int vb = blockIdx.x;
    const int t  = threadIdx.x;
    if (t < 64) {
        int v = (t < vb) ? blk[t] : 0;    // nvb <= 64
#pragma unroll
        for (int o = 32; o > 0; o >>= 1) v += __shfl_xor(v, o, 64);
        if (t == 0) s_add = v;
    }
    __syncthreads();
    const int add = s_add;
    const int base = vb * 1024 + t * 4;
    if (base + 3 < n) {
        int4 p = *reinterpret_cast<const int4*>(pre + base);
        p.x += add; p.y += add; p.z += add; p.w += add;
        *reinterpret_cast<int4*>(off + base) = p;
    } else {
#pragma unroll
        for (int k = 0; k < 4; ++k)
            if (base + k < n) off[base + k] = pre[base + k] + add;
    }
    if (vb == nvb - 1 && t == 0) off[n] = add + blk[vb];
}

// --- weight precompute (= scatter into permuted CSR order) ------------------

template <int H>
__global__ __launch_bounds__(256) void wkernel(
    const int* __restrict__ esrc, const int* __restrict__ edst,
    const int* __restrict__ rank, const int* __restrict__ off2,
    const int* __restrict__ inv,
    const float* __restrict__ a_s, const float* __restrict__ a_d,
    f32x2* __restrict__ sw,          // [H][E+N] head-major
    int N, int E)
{
    const int idx = blockIdx.x * 256 + threadIdx.x;
    int s, dd, pos;
    if (idx < N) {
        s = idx; dd = idx; pos = off2[inv[idx]];
    } else if (idx < N + E) {
        const int e = idx - N;
        s = esrc[e]; dd = edst[e];
        pos = off2[inv[dd]] + 1 + rank[e];
    } else {
        return;
    }
#pragma unroll
    for (int h = 0; h < H; ++h) {
        float lg = a_s[s * H + h] + a_d[dd * H + h];
        lg = lg > 0.f ? lg : 0.2f * lg;
        f32x2 v = { __int_as_float(s), __expf(lg) };
        sw[(size_t)h * (N + E) + pos] = v;
    }
}

// --- XCD-striped pull aggregation (degree-sorted, zero-overhead) -----------

template <int H, int C, bool RELU, typename TOUT>
__global__ __launch_bounds__(256) void aggregate_kernel(
    const int* __restrict__ off2,    // [N+1] permuted CSR offsets
    const int* __restrict__ perm,    // [N] k -> original dst id
    const f32x2* __restrict__ sw,    // [H][E+N] head-major, permuted order
    const _Float16* __restrict__ h,  // sliced [HC/32][N][32] fp16
    const float* __restrict__ bias,  // [HC]
    TOUT* __restrict__ out,          // f16: sliced [HC/32][N][32]; f32: [N,HC]
    int N, int ENtot, int G8)        // G8 = gridDim.x / 8
{
    constexpr int HC  = H * C;
    constexpr int NS  = HC / 32;     // slices: 8 (L1), 4 (L2)
    constexpr int REP = 8 / NS;      // XCD groups per slice
    const int w  = threadIdx.x >> 6;
    const int l  = threadIdx.x & 63;
    const int g  = l >> 2;           // group 0..15 (4 lanes each)
    const int cl = (l & 3) * 8;      // col base within slice (8 cols)
    const int b8 = blockIdx.x & 7;
    const int slice = b8 % NS;
    const int hh = (slice * 32) / C; // head of this slice

    const f32x2*    __restrict__ swh = sw + (size_t)hh * ENtot;
    const _Float16* __restrict__ hs  = h + (size_t)slice * N * 32;

    const int wid  = ((blockIdx.x >> 3) * REP + b8 / NS) * 4 + w;
    const int nwav = G8 * REP * 4;   // waves per slice

    for (int kb = wid * 16; kb < N; kb += nwav * 16) {
        const int k = kb + g;
        const bool act = k < N;
        int beg = 0, end = 0, d = 0;
        if (act) { d = perm[k]; beg = off2[k]; end = off2[k + 1]; }

        float a0 = 0.f, a1 = 0.f, a2 = 0.f, a3 = 0.f;
        float a4 = 0.f, a5 = 0.f, a6 = 0.f, a7 = 0.f, ws = 0.f;
#pragma unroll 2
        for (int e = beg; e < end; ++e) {
            const f32x2 sv = swh[e];
            const int    s  = __float_as_int(sv.x);
            const float  wt = sv.y;
            const half8v hv = *reinterpret_cast<const half8v*>(
                hs + (size_t)s * 32 + cl);
            a0 += wt * (float)hv[0];
            a1 += wt * (float)hv[1];
            a2 += wt * (float)hv[2];
            a3 += wt * (float)hv[3];
            a4 += wt * (float)hv[4];
            a5 += wt * (float)hv[5];
            a6 += wt * (float)hv[6];
            a7 += wt * (float)hv[7];
            ws += wt;
        }

        if (act) {
            const float inv_ = 1.f / ws;
            const int cb = slice * 32 + cl;
            float r[8];
            r[0] = a0 * inv_ + bias[cb + 0];
            r[1] = a1 * inv_ + bias[cb + 1];
            r[2] = a2 * inv_ + bias[cb + 2];
            r[3] = a3 * inv_ + bias[cb + 3];
            r[4] = a4 * inv_ + bias[cb + 4];
            r[5] = a5 * inv_ + bias[cb + 5];
            r[6] = a6 * inv_ + bias[cb + 6];
            r[7] = a7 * inv_ + bias[cb + 7];
            if (RELU) {
#pragma unroll
                for (int q = 0; q < 8; ++q) r[q] = r[q] > 0.f ? r[q] : 0.f;
            }
            if constexpr (__is_same(TOUT, _Float16)) {
                half8v ov;
#pragma unroll
                for (int q = 0; q < 8; ++q) ov[q] = (_Float16)r[q];
                *reinterpret_cast<half8v*>(
                    out + ((size_t)slice * N + d) * 32 + cl) = ov;
            } else {
                f32x4 o0 = { r[0], r[1], r[2], r[3] };
                f32x4 o1 = { r[4], r[5], r[6], r[7] };
                float* po = out + (size_t)d * HC + slice * 32 + cl;
                *reinterpret_cast<f32x4*>(po)     = o0;
                *reinterpret_cast<f32x4*>(po + 4) = o1;
            }
        }
    }
}

// ---------------------------------------------------------------------------

extern "C" void kernel_launch(void* const* d_in, const int* in_sizes, int n_in,
                              void* d_out, int out_size, void* d_ws, size_t ws_size,
                              hipStream_t stream)
{
    const float* x    = (const float*)d_in[0];
    const int*   eidx = (const int*)d_in[1];
    const float* W1   = (const float*)d_in[2];
    const float* as1  = (const float*)d_in[3];
    const float* ad1  = (const float*)d_in[4];
    const float* b1   = (const float*)d_in[5];
    const float* W2   = (const float*)d_in[6];
    const float* as2  = (const float*)d_in[7];
    const float* ad2  = (const float*)d_in[8];
    const float* b2   = (const float*)d_in[9];
    float* out = (float*)d_out;

    const int IN_FEATS = 256;
    const int N = in_sizes[0] / IN_FEATS;    // 50000
    const int E = in_sizes[1] / 2;           // 800000
    const int EN = E + N;

    const int* esrc = eidx;
    const int* edst = eidx + E;

    size_t off = 0;
    auto alloc = [&](size_t bytes) -> void* {
        void* p = (char*)d_ws + off;
        off += (bytes + 255) & ~(size_t)255;
        return p;
    };
    _Float16* h1h   = (_Float16*)alloc((size_t)N * 256 * 2);   // sliced [8][N][32]
    _Float16* o1h   = (_Float16*)alloc((size_t)N * 256 * 2);   // sliced [8][N][32]
    _Float16* h2h   = (_Float16*)alloc((size_t)N * 128 * 2);   // sliced [4][N][32]
    float* a1s      = (float*)alloc((size_t)N * 2 * 4);
    float* a1d      = (float*)alloc((size_t)N * 2 * 4);
    float* a2s      = (float*)alloc((size_t)N * 4);
    float* a2d      = (float*)alloc((size_t)N * 4);
    int*   deg      = (int*)alloc((size_t)N * 4);
    int*   pre      = (int*)alloc((size_t)N * 4);
    int*   rank     = (int*)alloc((size_t)E * 4);
    int*   off2     = (int*)alloc((size_t)(N + 1) * 4);
    int*   perm     = (int*)alloc((size_t)N * 4);
    int*   invp     = (int*)alloc((size_t)N * 4);
    int*   hist     = (int*)alloc(256 * 4);
    int*   bincur   = (int*)alloc(256 * 4);
    f32x2* sw1      = (f32x2*)alloc((size_t)2 * EN * 8);       // [2][E+N]
    int*   blk      = (int*)alloc(64 * 4);
    // sw2 aliases h1h (h1h dead after agg1; wkernel<1>/agg2 run later)
    f32x2* sw2      = (f32x2*)h1h;                             // [1][E+N]

    const int nvb = (N + 1023) / 1024;    // 49 <= 64

    // --- CSR offsets + ranks + degree counting sort ---
    (void)hipMemsetAsync(deg, 0, (size_t)N * 4, stream);
    (void)hipMemsetAsync(hist, 0, 256 * 4, stream);
    count_kernel<<<((E + 3) / 4 + 255) / 256, 256, 0, stream>>>(edst, deg, rank, E);
    hist_kernel<<<nvb, 256, 0, stream>>>(deg, hist, N);
    scan256_kernel<<<1, 256, 0, stream>>>(hist, bincur);
    scatter_perm_kernel<<<nvb, 256, 0, stream>>>(deg, bincur, perm, invp, N);
    block_scan_perm_kernel<<<nvb, 256, 0, stream>>>(deg, perm, pre, blk, N);
    finalize_scan_kernel<<<nvb, 256, 0, stream>>>(pre, blk, off2, N, nvb);

    // --- layer 1 ---
    {
        const int GB = (N + 127) / 128;      // 392 (multiple of 8)
        gemm_att_kernel<float, 2><<<GB * 2, 256, 0, stream>>>(
            x, W1, h1h, as1, ad1, a1s, a1d, N, 256, GB);
    }
    wkernel<2><<<(EN + 255) / 256, 256, 0, stream>>>(
        esrc, edst, rank, off2, invp, a1s, a1d, sw1, N, E);
    {
        const int G8 = 256;                  // 2048 blocks co-resident
        aggregate_kernel<2, 128, true, _Float16><<<G8 * 8, 256, 0, stream>>>(
            off2, perm, sw1, h1h, b1, o1h, N, EN, G8);
    }

    // --- layer 2 ---
    {
        const int GB = (N + 127) / 128;
        gemm_att_kernel<_Float16, 1><<<GB, 256, 0, stream>>>(
            o1h, W2, h2h, as2, ad2, a2s, a2d, N, 256, GB);
    }
    wkernel<1><<<(EN + 255) / 256, 256, 0, stream>>>(
        esrc, edst, rank, off2, invp, a2s, a2d, sw2, N, E);
    {
        const int G8 = 256;
        aggregate_kernel<1, 128, false, float><<<G8 * 8, 256, 0, stream>>>(
            off2, perm, sw2, h2h, b2, out, N, EN, G8);
    }
}